// Round 6
// baseline (1037.201 us; speedup 1.0000x reference)
//
#include <hip/hip_runtime.h>
#include <hip/hip_bf16.h>
#include <hip/hip_fp16.h>
#include <math.h>

// GNN: 3-layer GCN + BN + GELU + residual + meanpool + MLP -> scalar.
// R6: agg rebuilt for memory-level parallelism. R5 post-mortem: VGPR_Count=32
// starved the allocator (4 uint4 + 16 acc floats = 32 regs, zero left) ->
// loads serialized -> 1.66 TB/s. Fix: __launch_bounds__(256,4) (128-VGPR cap),
// R2's winning wave shape (32 lanes/node, 2 nodes/wave), 8B lane loads,
// 8-edge batched gathers (8 loads in flight). fp16 table kept (halved bytes).

__device__ __forceinline__ float gelu_f(float x) {
    return 0.5f * x * (1.0f + erff(x * 0.7071067811865476f));
}

__device__ __forceinline__ int wave_incl_scan(int v, int lane) {
#pragma unroll
    for (int off = 1; off < 64; off <<= 1) {
        int t = __shfl_up(v, (unsigned)off, 64);
        if (lane >= off) v += t;
    }
    return v;
}

// load-type per channels-per-lane
template <int CPL> struct LoadT;
template <> struct LoadT<4> { using T = uint2; };
template <> struct LoadT<2> { using T = unsigned int; };

__device__ __forceinline__ void accH(unsigned int u, float* f) {
    float2 t = __half22float2(*(const __half2*)&u);
    f[0] += t.x; f[1] += t.y;
}
__device__ __forceinline__ void accH(uint2 u, float* f) {
    accH(u.x, f); accH(u.y, f + 2);
}

// ---- init: deg = 1.0 (self loop), zero double accumulators ----
__global__ void init_kernel(float* __restrict__ deg, double* __restrict__ dbls,
                            int n, int ndbl) {
    int i = blockIdx.x * 256 + threadIdx.x;
    if (i < n) deg[i] = 1.0f;
    if (i < ndbl) dbls[i] = 0.0;
}

__global__ void degree_kernel(const int* __restrict__ col, float* __restrict__ deg, int E) {
    int e = blockIdx.x * 256 + threadIdx.x;
    if (e < E) atomicAdd(&deg[col[e]], 1.0f);
}

__global__ __launch_bounds__(256) void scan1_kernel(const float* __restrict__ deg,
                                                    float* __restrict__ dinv,
                                                    int* __restrict__ offs,
                                                    int* __restrict__ bsums, int n) {
    int i = blockIdx.x * 256 + threadIdx.x;
    int lane = threadIdx.x & 63;
    int wid = threadIdx.x >> 6;
    int cnt = 0;
    if (i < n) {
        float d = deg[i];
        dinv[i] = 1.0f / sqrtf(d);
        cnt = (int)d - 1;
    }
    int incl = wave_incl_scan(cnt, lane);
    __shared__ int ws[4];
    if (lane == 63) ws[wid] = incl;
    __syncthreads();
    if (threadIdx.x == 0) {
        int a = 0;
#pragma unroll
        for (int j = 0; j < 4; j++) { int t = ws[j]; ws[j] = a; a += t; }
        bsums[blockIdx.x] = a;
    }
    __syncthreads();
    int excl = incl - cnt + ws[wid];
    if (i < n) offs[i] = excl;
}

__global__ __launch_bounds__(512) void scan2_kernel(int* __restrict__ bsums, int nblk) {
    int lane = threadIdx.x & 63;
    int wid = threadIdx.x >> 6;
    int v = (threadIdx.x < nblk) ? bsums[threadIdx.x] : 0;
    int incl = wave_incl_scan(v, lane);
    __shared__ int ws[8];
    if (lane == 63) ws[wid] = incl;
    __syncthreads();
    if (threadIdx.x == 0) {
        int a = 0;
#pragma unroll
        for (int j = 0; j < 8; j++) { int t = ws[j]; ws[j] = a; a += t; }
    }
    __syncthreads();
    int excl = incl - v + ws[wid];
    if (threadIdx.x < nblk) bsums[threadIdx.x] = excl;
}

__global__ void scan3_kernel(int* __restrict__ offs, const int* __restrict__ bsums,
                             int* __restrict__ cursor, int n) {
    int i = blockIdx.x * 256 + threadIdx.x;
    if (i < n) {
        int o = offs[i] + bsums[i >> 8];
        offs[i] = o;
        cursor[i] = o;
    }
}

__global__ void fill_kernel(const int* __restrict__ row, const int* __restrict__ col,
                            int* __restrict__ cursor, int* __restrict__ csr, int E) {
    int e = blockIdx.x * 256 + threadIdx.x;
    if (e < E) {
        int c = col[e];
        int pos = atomicAdd(&cursor[c], 1);
        csr[pos] = row[e];
    }
}

// ---- convert x[N][64] fp32 -> xh[N][64] fp16, scaled by dinv[node] ----
__global__ __launch_bounds__(256) void halfconv_kernel(const float* __restrict__ x,
                                                       const float* __restrict__ dinv,
                                                       __half* __restrict__ xh, int N) {
    int t = blockIdx.x * 256 + threadIdx.x;   // one 8-float chunk per thread
    if (t >= N * 8) return;
    int node = t >> 3;
    float dv = dinv[node];
    const float4* p = (const float4*)(x + (size_t)t * 8);
    float4 a = p[0], b = p[1];
    __half2 h[4];
    h[0] = __floats2half2_rn(a.x * dv, a.y * dv);
    h[1] = __floats2half2_rn(a.z * dv, a.w * dv);
    h[2] = __floats2half2_rn(b.x * dv, b.y * dv);
    h[3] = __floats2half2_rn(b.z * dv, b.w * dv);
    *(uint4*)(xh + (size_t)t * 8) = *(uint4*)h;
}

// ---- aggregation: H[i][D] = dinv_i*(Ut[i] + sum in-edge Ut[src]) (+bias) ----
// Ut fp16 row-major, pre-scaled by dinv[src]; fp32 accumulate.
// 32 lanes/node (2 nodes/wave), CPL=D/32 channels per lane, 8-edge batches.
template <int D, bool STATS, bool BIAS>
__global__ __launch_bounds__(256, 4) void agg_kernel(const __half* __restrict__ Ut,
                                                     const int* __restrict__ csr,
                                                     const int* __restrict__ offs,
                                                     const float* __restrict__ deg,
                                                     const float* __restrict__ dinv,
                                                     const float* __restrict__ bias,
                                                     float* __restrict__ H,
                                                     double* __restrict__ stats, int n) {
    constexpr int LPN = 32;            // lanes per node
    constexpr int CPL = D / LPN;       // channels per lane: 4 (D=128) / 2 (D=64)
    constexpr int NPB = 256 / LPN;     // 8 nodes per block
    using LT = typename LoadT<CPL>::T;

    int g = threadIdx.x >> 5;
    int cl = threadIdx.x & 31;
    int node = blockIdx.x * NPB + g;
    bool act = node < n;

    float a[CPL], b[CPL];
#pragma unroll
    for (int c = 0; c < CPL; c++) { a[c] = 0.f; b[c] = 0.f; }

    int start = 0, cnt = 0;
    float dvi = 0.f;
    if (act) {
        start = offs[node];
        cnt = (int)deg[node] - 1;
        dvi = dinv[node];
        LT u = *(const LT*)(Ut + (size_t)node * D + cl * CPL);   // self (pre-scaled)
        accH(u, a);
    }
    const __half* __restrict__ base = Ut + cl * CPL;
    int j = 0;
    for (; j + 8 <= cnt; j += 8) {
        int s[8];
#pragma unroll
        for (int t = 0; t < 8; t++) s[t] = csr[start + j + t];
        LT u[8];
#pragma unroll
        for (int t = 0; t < 8; t++) u[t] = *(const LT*)(base + (size_t)s[t] * D);
#pragma unroll
        for (int t = 0; t < 8; t++) accH(u[t], (t & 1) ? b : a);
    }
    if (j + 4 <= cnt) {
        int s[4];
#pragma unroll
        for (int t = 0; t < 4; t++) s[t] = csr[start + j + t];
        LT u[4];
#pragma unroll
        for (int t = 0; t < 4; t++) u[t] = *(const LT*)(base + (size_t)s[t] * D);
#pragma unroll
        for (int t = 0; t < 4; t++) accH(u[t], (t & 1) ? b : a);
        j += 4;
    }
    if (j + 2 <= cnt) {
        int s0 = csr[start + j], s1 = csr[start + j + 1];
        LT u0 = *(const LT*)(base + (size_t)s0 * D);
        LT u1 = *(const LT*)(base + (size_t)s1 * D);
        accH(u0, a); accH(u1, b);
        j += 2;
    }
    if (j < cnt) {
        int s0 = csr[start + j];
        LT u0 = *(const LT*)(base + (size_t)s0 * D);
        accH(u0, a);
    }

    float h[CPL];
#pragma unroll
    for (int c = 0; c < CPL; c++) h[c] = (a[c] + b[c]) * dvi;
    if (BIAS) {
#pragma unroll
        for (int c = 0; c < CPL; c++) h[c] += bias[cl * CPL + c];
    }
    if (act) {
        float* dst = H + (size_t)node * D + cl * CPL;
        if (CPL == 4)
            *(float4*)dst = make_float4(h[0], h[1], h[2], h[3]);
        else
            *(float2*)dst = make_float2(h[0], h[1]);
    } else {
#pragma unroll
        for (int c = 0; c < CPL; c++) h[c] = 0.f;   // no stats contribution
    }

    if (STATS) {
        float s[CPL], q[CPL];
#pragma unroll
        for (int c = 0; c < CPL; c++) { s[c] = h[c]; q[c] = h[c] * h[c]; }
        // fold the 2 nodes of the wave (lane ^ 32)
#pragma unroll
        for (int c = 0; c < CPL; c++) {
            s[c] += __shfl_xor(s[c], 32, 64);
            q[c] += __shfl_xor(q[c], 32, 64);
        }
        __shared__ float ps[4][32][CPL], pq[4][32][CPL];
        int wid = threadIdx.x >> 6;
        int lane = threadIdx.x & 63;
        if (lane < 32) {
#pragma unroll
            for (int c = 0; c < CPL; c++) { ps[wid][lane][c] = s[c]; pq[wid][lane][c] = q[c]; }
        }
        __syncthreads();
        if (threadIdx.x < D) {
            int cgi = threadIdx.x / CPL, ci = threadIdx.x % CPL;
            float t1 = ps[0][cgi][ci] + ps[1][cgi][ci] + ps[2][cgi][ci] + ps[3][cgi][ci];
            float t2 = pq[0][cgi][ci] + pq[1][cgi][ci] + pq[2][cgi][ci] + pq[3][cgi][ci];
            atomicAdd(&stats[threadIdx.x], (double)t1);
            atomicAdd(&stats[D + threadIdx.x], (double)t2);
        }
    }
}

// ---- register-blocked GEMM ----
template <int DIN, int DOUT, bool BNIN, bool BIAS, bool DINVOUT, bool HALFOUT, bool STATS>
__global__ __launch_bounds__(256) void gemm_kernel(const float* __restrict__ Hin,
                                                   const float* __restrict__ W,
                                                   const float* __restrict__ scale,
                                                   const float* __restrict__ shift,
                                                   const float* __restrict__ bias,
                                                   const float* __restrict__ dinv,
                                                   float* __restrict__ Out,
                                                   double* __restrict__ stats, int n) {
    constexpr int BNODES = 64;
    constexpr int KT = 32;
    constexpr int HP = DIN + 4;
    constexpr int VC = DOUT / 16;      // 8 (DOUT=128) or 4 (DOUT=64)
    constexpr int C4 = VC / 4;
    __shared__ float Hs[BNODES * HP];
    __shared__ float Ws[KT * DOUT];
    __shared__ float ps[STATS ? 4 : 1][16][VC];
    __shared__ float pq[STATS ? 4 : 1][16][VC];

    int node0 = blockIdx.x * BNODES;
    int nv = n - node0;
    if (nv > BNODES) nv = BNODES;
    int cg = threadIdx.x & 15;
    int ng = threadIdx.x >> 4;

    constexpr int F4 = BNODES * (DIN / 4);
    for (int f = threadIdx.x; f < F4; f += 256) {
        int nn = f / (DIN / 4);
        int k4 = f - nn * (DIN / 4);
        float4 v = make_float4(0.f, 0.f, 0.f, 0.f);
        if (nn < nv)
            v = *(const float4*)(Hin + (size_t)(node0 + nn) * DIN + k4 * 4);
        if (BNIN) {
            float4 sc = *(const float4*)(scale + k4 * 4);
            float4 sh = *(const float4*)(shift + k4 * 4);
            v.x = gelu_f(fmaf(v.x, sc.x, sh.x));
            v.y = gelu_f(fmaf(v.y, sc.y, sh.y));
            v.z = gelu_f(fmaf(v.z, sc.z, sh.z));
            v.w = gelu_f(fmaf(v.w, sc.w, sh.w));
        }
        *(float4*)(Hs + nn * HP + k4 * 4) = v;
    }

    float acc[4][VC];
#pragma unroll
    for (int i = 0; i < 4; i++)
#pragma unroll
        for (int c = 0; c < VC; c++) acc[i][c] = 0.0f;

    for (int kb = 0; kb < DIN; kb += KT) {
        __syncthreads();
        for (int f = threadIdx.x; f < KT * DOUT / 4; f += 256)
            *(float4*)(Ws + f * 4) = *(const float4*)(W + (size_t)kb * DOUT + f * 4);
        __syncthreads();
#pragma unroll
        for (int kk = 0; kk < KT; kk++) {
            float h[4];
#pragma unroll
            for (int i = 0; i < 4; i++)
                h[i] = Hs[(ng * 4 + i) * HP + kb + kk];
            float w[VC];
#pragma unroll
            for (int c = 0; c < C4; c++) {
                float4 w4 = *(const float4*)(Ws + kk * DOUT + cg * VC + c * 4);
                w[c * 4 + 0] = w4.x; w[c * 4 + 1] = w4.y;
                w[c * 4 + 2] = w4.z; w[c * 4 + 3] = w4.w;
            }
#pragma unroll
            for (int i = 0; i < 4; i++)
#pragma unroll
                for (int c = 0; c < VC; c++)
                    acc[i][c] = fmaf(h[i], w[c], acc[i][c]);
        }
    }

    float fin[4][VC];
#pragma unroll
    for (int i = 0; i < 4; i++) {
        int nn = ng * 4 + i;
        bool valid = nn < nv;
        int node = node0 + nn;
        float dv = 1.0f;
        if (DINVOUT && valid) dv = dinv[node];
#pragma unroll
        for (int c = 0; c < VC; c++) {
            float f = acc[i][c] * dv;
            if (BIAS) f += bias[cg * VC + c];
            fin[i][c] = valid ? f : 0.f;
        }
        if (valid) {
            if (HALFOUT) {
                __half* hp = (__half*)Out + (size_t)node * DOUT + cg * VC;
                if (VC == 8) {
                    __half2 pk[4];
                    pk[0] = __floats2half2_rn(fin[i][0], fin[i][1]);
                    pk[1] = __floats2half2_rn(fin[i][2], fin[i][3]);
                    pk[2] = __floats2half2_rn(fin[i][4], fin[i][5]);
                    pk[3] = __floats2half2_rn(fin[i][6], fin[i][7]);
                    *(uint4*)hp = *(uint4*)pk;
                } else {
                    __half2 pk[2];
                    pk[0] = __floats2half2_rn(fin[i][0], fin[i][1]);
                    pk[1] = __floats2half2_rn(fin[i][2], fin[i][3]);
                    *(uint2*)hp = *(uint2*)pk;
                }
            } else {
#pragma unroll
                for (int c = 0; c < C4; c++)
                    *(float4*)(Out + (size_t)node * DOUT + cg * VC + c * 4) =
                        make_float4(fin[i][c * 4 + 0], fin[i][c * 4 + 1],
                                    fin[i][c * 4 + 2], fin[i][c * 4 + 3]);
            }
        }
    }

    if (STATS) {
        float s[VC], q[VC];
#pragma unroll
        for (int c = 0; c < VC; c++) {
            s[c] = fin[0][c] + fin[1][c] + fin[2][c] + fin[3][c];
            q[c] = fin[0][c] * fin[0][c] + fin[1][c] * fin[1][c] +
                   fin[2][c] * fin[2][c] + fin[3][c] * fin[3][c];
        }
#pragma unroll
        for (int st = 16; st < 64; st <<= 1) {
#pragma unroll
            for (int c = 0; c < VC; c++) {
                s[c] += __shfl_xor(s[c], st, 64);
                q[c] += __shfl_xor(q[c], st, 64);
            }
        }
        int wid = threadIdx.x >> 6;
        int lane = threadIdx.x & 63;
        if (lane < 16) {
#pragma unroll
            for (int c = 0; c < VC; c++) { ps[wid][lane][c] = s[c]; pq[wid][lane][c] = q[c]; }
        }
        __syncthreads();
        if (threadIdx.x < DOUT) {
            int col = threadIdx.x;
            int cgi = col / VC, ci = col % VC;
            float t = ps[0][cgi][ci] + ps[1][cgi][ci] + ps[2][cgi][ci] + ps[3][cgi][ci];
            float t2 = pq[0][cgi][ci] + pq[1][cgi][ci] + pq[2][cgi][ci] + pq[3][cgi][ci];
            atomicAdd(&stats[col], (double)t);
            atomicAdd(&stats[DOUT + col], (double)t2);
        }
    }
}

// ---- stats sums -> per-channel scale/shift floats ----
template <int D>
__global__ void finalize_kernel(const double* __restrict__ stats,
                                const float* __restrict__ g, const float* __restrict__ be,
                                float* __restrict__ scale, float* __restrict__ shift, int n) {
    int c = threadIdx.x;
    if (c < D) {
        double mu = stats[c] / n;
        double var = stats[c + D] / n - mu * mu;
        double inv = 1.0 / sqrt(var + 1e-5);
        double sc = (double)g[c] * inv;
        scale[c] = (float)sc;
        shift[c] = (float)((double)be[c] - mu * sc);
    }
}

// ---- layer-3: BN normalize + GELU + residual(x) + mean-pool accumulate ----
__global__ __launch_bounds__(256) void norm_pool_kernel(const float* __restrict__ X3,
                                                        const float* __restrict__ x0,
                                                        const double* __restrict__ stats,
                                                        const float* __restrict__ gw,
                                                        const float* __restrict__ be,
                                                        double* __restrict__ pool, int n) {
    constexpr int D = 64;
    constexpr int RPB = 4;
    int c = threadIdx.x % D;
    double mu = stats[c] / n;
    double var = stats[c + D] / n - mu * mu;
    double inv = 1.0 / sqrt(var + 1e-5);
    float scale = (float)((double)gw[c] * inv);
    float shift = (float)((double)be[c] - mu * (double)gw[c] * inv);
    int r0 = threadIdx.x / D;
    int rowsPerGrid = gridDim.x * RPB;
    double s = 0.0;
    for (int r = blockIdx.x * RPB + r0; r < n; r += rowsPerGrid) {
        size_t idx = (size_t)r * D + c;
        float t = fmaf(X3[idx], scale, shift);
        float res = x0[idx] + gelu_f(t);
        s += res;
    }
    __shared__ double sh[256];
    sh[threadIdx.x] = s;
    __syncthreads();
    if (threadIdx.x < D) {
#pragma unroll
        for (int j = 1; j < RPB; j++) s += sh[threadIdx.x + j * D];
        atomicAdd(&pool[c], s);
    }
}

// ---- head MLP: 64 ->128 ->64 ->32 ->1, single block ----
__global__ __launch_bounds__(128) void mlp_kernel(const double* __restrict__ pool,
                                                  const float* __restrict__ w1, const float* __restrict__ b1,
                                                  const float* __restrict__ w2, const float* __restrict__ b2,
                                                  const float* __restrict__ w3, const float* __restrict__ b3,
                                                  const float* __restrict__ w4, const float* __restrict__ b4,
                                                  float* __restrict__ out, int n) {
    __shared__ float v0[64], h1[128], h2[64], h3[32];
    int t = threadIdx.x;
    if (t < 64) v0[t] = (float)(pool[t] / (double)n);
    __syncthreads();
    if (t < 128) {
        float a = b1[t];
        for (int k = 0; k < 64; k++) a = fmaf(v0[k], w1[k * 128 + t], a);
        h1[t] = gelu_f(a);
    }
    __syncthreads();
    if (t < 64) {
        float a = b2[t];
        for (int k = 0; k < 128; k++) a = fmaf(h1[k], w2[k * 64 + t], a);
        h2[t] = gelu_f(a);
    }
    __syncthreads();
    if (t < 32) {
        float a = b3[t];
        for (int k = 0; k < 64; k++) a = fmaf(h2[k], w3[k * 32 + t], a);
        h3[t] = gelu_f(a);
    }
    __syncthreads();
    if (t == 0) {
        float a = b4[0];
        for (int k = 0; k < 32; k++) a = fmaf(h3[k], w4[k], a);
        out[0] = a;
    }
}

extern "C" void kernel_launch(void* const* d_in, const int* in_sizes, int n_in,
                              void* d_out, int out_size, void* d_ws, size_t ws_size,
                              hipStream_t stream) {
    const float* x    = (const float*)d_in[0];
    const int*   ei   = (const int*)d_in[1];
    const float* W1   = (const float*)d_in[2];
    const float* b1   = (const float*)d_in[3];
    const float* g1   = (const float*)d_in[4];
    const float* be1  = (const float*)d_in[5];
    const float* W2   = (const float*)d_in[6];
    const float* b2   = (const float*)d_in[7];
    const float* g2   = (const float*)d_in[8];
    const float* be2  = (const float*)d_in[9];
    const float* W3   = (const float*)d_in[10];
    const float* b3   = (const float*)d_in[11];
    const float* g3   = (const float*)d_in[12];
    const float* be3  = (const float*)d_in[13];
    const float* fc1w = (const float*)d_in[14];
    const float* fc1b = (const float*)d_in[15];
    const float* fc2w = (const float*)d_in[16];
    const float* fc2b = (const float*)d_in[17];
    const float* fc3w = (const float*)d_in[18];
    const float* fc3b = (const float*)d_in[19];
    const float* fc4w = (const float*)d_in[20];
    const float* fc4b = (const float*)d_in[21];

    const int N = in_sizes[0] / 64;
    const int E = in_sizes[1] / 2;
    const int* e_row = ei;       // source
    const int* e_col = ei + E;   // target (aggregation index)

    // ---- workspace layout (~110 MB) ----
    char* ws = (char*)d_ws;
    size_t off = 0;
    double* stats1 = (double*)(ws + off); off += 256 * sizeof(double);
    double* stats2 = (double*)(ws + off); off += 256 * sizeof(double);
    double* stats3 = (double*)(ws + off); off += 256 * sizeof(double);
    double* pool   = (double*)(ws + off); off += 64 * sizeof(double);
    float* scale1 = (float*)(ws + off); off += 128 * sizeof(float);
    float* shift1 = (float*)(ws + off); off += 128 * sizeof(float);
    float* scale2 = (float*)(ws + off); off += 128 * sizeof(float);
    float* shift2 = (float*)(ws + off); off += 128 * sizeof(float);
    float* deg   = (float*)(ws + off); off += (size_t)N * sizeof(float);
    float* dinv  = (float*)(ws + off); off += (size_t)N * sizeof(float);
    off = (off + 15) & ~(size_t)15;
    int* offs    = (int*)(ws + off); off += (size_t)N * sizeof(int);
    int* cursor  = (int*)(ws + off); off += (size_t)N * sizeof(int);
    int* bsums   = (int*)(ws + off); off += 512 * sizeof(int);
    int* csr     = (int*)(ws + off); off += (size_t)E * sizeof(int);
    off = (off + 255) & ~(size_t)255;
    __half* Ut   = (__half*)(ws + off); off += (size_t)N * 128 * sizeof(__half);  // fp16 gather table
    float* A1    = (float*)(ws + off);  off += (size_t)N * 64 * sizeof(float);    // agg1 out (fp32)
    float* H     = (float*)(ws + off);  off += (size_t)N * 128 * sizeof(float);   // fp32 row-major
    __half* xh   = Ut;  // alias: xh dead after agg1, before gemm2 writes Ut

    const int nb256 = (N + 255) / 256;
    const int ebl = (E + 255) / 256;
    const int aggblk = (N + 7) / 8;     // 8 nodes per agg block

    init_kernel<<<nb256, 256, 0, stream>>>(deg, stats1, N, 832);
    degree_kernel<<<ebl, 256, 0, stream>>>(e_col, deg, E);
    scan1_kernel<<<nb256, 256, 0, stream>>>(deg, dinv, offs, bsums, N);
    scan2_kernel<<<1, 512, 0, stream>>>(bsums, nb256);
    scan3_kernel<<<nb256, 256, 0, stream>>>(offs, bsums, cursor, N);
    fill_kernel<<<ebl, 256, 0, stream>>>(e_row, e_col, cursor, csr, E);

    // Layer 1: x -> fp16 (dinv-scaled); agg 64-dim -> A1; GEMM(+b1,+stats1) -> H1
    halfconv_kernel<<<(N * 8 + 255) / 256, 256, 0, stream>>>(x, dinv, xh, N);
    agg_kernel<64, false, false><<<aggblk, 256, 0, stream>>>(
        xh, csr, offs, deg, dinv, nullptr, A1, nullptr, N);
    gemm_kernel<64, 128, false, true, false, false, true><<<(N + 63) / 64, 256, 0, stream>>>(
        A1, W1, nullptr, nullptr, b1, dinv, H, stats1, N);
    finalize_kernel<128><<<1, 128, 0, stream>>>(stats1, g1, be1, scale1, shift1, N);

    // Layer 2: GEMM (BN1+GELU fused, dinv-scaled, fp16 out) -> Ut; agg(+b2,+stats2) -> H2
    gemm_kernel<128, 128, true, false, true, true, false><<<(N + 63) / 64, 256, 0, stream>>>(
        H, W2, scale1, shift1, nullptr, dinv, (float*)Ut, nullptr, N);
    agg_kernel<128, true, true><<<aggblk, 256, 0, stream>>>(
        Ut, csr, offs, deg, dinv, b2, H, stats2, N);
    finalize_kernel<128><<<1, 128, 0, stream>>>(stats2, g2, be2, scale2, shift2, N);

    // Layer 3: GEMM (BN2+GELU fused, fp16 out 64) -> Ut; agg(+b3,+stats3) -> H3
    gemm_kernel<128, 64, true, false, true, true, false><<<(N + 63) / 64, 256, 0, stream>>>(
        H, W3, scale2, shift2, nullptr, dinv, (float*)Ut, nullptr, N);
    agg_kernel<64, true, true><<<aggblk, 256, 0, stream>>>(
        Ut, csr, offs, deg, dinv, b3, H, stats3, N);

    // Epilogue: BN3+GELU+residual+meanpool, then head MLP
    norm_pool_kernel<<<1024, 256, 0, stream>>>(H, x, stats3, g3, be3, pool, N);
    mlp_kernel<<<1, 128, 0, stream>>>(pool, fc1w, fc1b, fc2w, fc2b, fc3w, fc3b,
                                      fc4w, fc4b, (float*)d_out, N);
}